// Round 13
// baseline (303.717 us; speedup 1.0000x reference)
//
#include <hip/hip_runtime.h>
#include <hip/hip_bf16.h>
#include <math.h>

// Sizes per reference: DIN=128, H=2, C=64, H*C=128, NUM_CLASSES=4
// NOTE: packing below requires N < 65536 (harness: N=50000).
#define HC   128
#define CCH  64
#define NBKE 512   // edge-processing blocks in fused bin+place (2 per CU; r12->r13)
#define GSTB 128   // stats blocks (atomic-free partials; compile-time for unroll)

typedef __attribute__((ext_vector_type(8))) short short8;
typedef __attribute__((ext_vector_type(4))) float floatx4;

__device__ __forceinline__ unsigned short f2bf(float f) {
  unsigned u = __float_as_uint(f);
  u += 0x7fffu + ((u >> 16) & 1u);  // RNE
  return (unsigned short)(u >> 16);
}

__device__ __forceinline__ void unpack8(uint4 u, float* f) {
  f[0] = __uint_as_float(u.x << 16);
  f[1] = __uint_as_float(u.x & 0xffff0000u);
  f[2] = __uint_as_float(u.y << 16);
  f[3] = __uint_as_float(u.y & 0xffff0000u);
  f[4] = __uint_as_float(u.z << 16);
  f[5] = __uint_as_float(u.z & 0xffff0000u);
  f[6] = __uint_as_float(u.w << 16);
  f[7] = __uint_as_float(u.w & 0xffff0000u);
}

// full-rate VALU lane-sum step: x += lane[ctrl-permuted x] (no LDS, no waitcnt)
template <int CTRL>
__device__ __forceinline__ float dpp_add(float x) {
  int t = __builtin_amdgcn_update_dpp(0, __float_as_int(x), CTRL, 0xf, 0xf, true);
  return x + __int_as_float(t);
}

// 32-row dual-side GEMM tile: 4 waves = {L,R} x {cols 0-63, 64-127},
// each wave does 2 row-groups of 16 against the SAME B registers
// (8 independent MFMAs per k-step, 0.75 loads/MFMA). Verified r1-r12.
template <int K>
__device__ __forceinline__ void gemm32rows(
    const unsigned short* __restrict__ A,
    const unsigned short* __restrict__ Wlt, const unsigned short* __restrict__ Wrt,
    const float* __restrict__ bl, const float* __restrict__ br,
    unsigned short* __restrict__ xlb, unsigned short* __restrict__ xrb,
    int M, int row0, int tid) {
  const int w = tid >> 6;
  const int lane = tid & 63;
  const bool isR = w >= 2;
  const unsigned short* Wt = isR ? Wrt : Wlt;
  const float* bias = isR ? br : bl;
  unsigned short* out = isR ? xrb : xlb;
  const int col0 = (w & 1) * 64;
  const int mrow = lane & 15, quad = lane >> 4;
  const unsigned short* pa0 = A + (size_t)(row0 + mrow) * K + quad * 8;
  const unsigned short* pa1 = pa0 + (size_t)16 * K;
  const unsigned short* pb = Wt + (size_t)(col0 + mrow) * K + quad * 8;
  floatx4 acc[2][4];
#pragma unroll
  for (int gp = 0; gp < 2; gp++)
#pragma unroll
    for (int ct = 0; ct < 4; ct++) acc[gp][ct] = (floatx4){0.f, 0.f, 0.f, 0.f};
#pragma unroll
  for (int k0 = 0; k0 < K; k0 += 32) {
    short8 a0 = *(const short8*)(pa0 + k0);
    short8 a1 = *(const short8*)(pa1 + k0);
    short8 b0 = *(const short8*)(pb + k0);
    short8 b1 = *(const short8*)(pb + 16 * K + k0);
    short8 b2 = *(const short8*)(pb + 32 * K + k0);
    short8 b3 = *(const short8*)(pb + 48 * K + k0);
    acc[0][0] = __builtin_amdgcn_mfma_f32_16x16x32_bf16(a0, b0, acc[0][0], 0, 0, 0);
    acc[1][0] = __builtin_amdgcn_mfma_f32_16x16x32_bf16(a1, b0, acc[1][0], 0, 0, 0);
    acc[0][1] = __builtin_amdgcn_mfma_f32_16x16x32_bf16(a0, b1, acc[0][1], 0, 0, 0);
    acc[1][1] = __builtin_amdgcn_mfma_f32_16x16x32_bf16(a1, b1, acc[1][1], 0, 0, 0);
    acc[0][2] = __builtin_amdgcn_mfma_f32_16x16x32_bf16(a0, b2, acc[0][2], 0, 0, 0);
    acc[1][2] = __builtin_amdgcn_mfma_f32_16x16x32_bf16(a1, b2, acc[1][2], 0, 0, 0);
    acc[0][3] = __builtin_amdgcn_mfma_f32_16x16x32_bf16(a0, b3, acc[0][3], 0, 0, 0);
    acc[1][3] = __builtin_amdgcn_mfma_f32_16x16x32_bf16(a1, b3, acc[1][3], 0, 0, 0);
  }
#pragma unroll
  for (int gp = 0; gp < 2; gp++) {
#pragma unroll
    for (int ct = 0; ct < 4; ct++) {
      int col = col0 + ct * 16 + mrow;
      float bv = bias[col];
#pragma unroll
      for (int r = 0; r < 4; r++) {
        int row = row0 + gp * 16 + quad * 4 + r;
        if (row < M) out[(size_t)row * HC + col] = f2bf(acc[gp][ct][r] + bv);
      }
    }
  }
}

// ========== K1: fused multisplit count+place (blocks < NBKE) ∥ casts =========
__global__ __launch_bounds__(256) void binplace_cast(
    const int* __restrict__ ei, int E, int chunk, int nB, int cap,
    int* __restrict__ gCnt, unsigned* __restrict__ ebuf,
    const float* __restrict__ x, unsigned short* __restrict__ xb, int cnt4,
    const float* __restrict__ Wl, const float* __restrict__ Wr,
    unsigned short* __restrict__ Wlt, unsigned short* __restrict__ Wrt) {
  if ((int)blockIdx.x < NBKE) {
    __shared__ int cnt[512];
    for (int j = threadIdx.x; j < nB; j += 256) cnt[j] = 0;
    __syncthreads();
    int e0 = blockIdx.x * chunk;
    int e1 = e0 + chunk; e1 = e1 < E ? e1 : E;
    int e = e0 + threadIdx.x;
    for (; e + 768 < e1; e += 1024) {
      int d0 = ei[E + e];
      int d1 = ei[E + e + 256];
      int d2 = ei[E + e + 512];
      int d3 = ei[E + e + 768];
      atomicAdd(&cnt[d0 >> 7], 1);
      atomicAdd(&cnt[d1 >> 7], 1);
      atomicAdd(&cnt[d2 >> 7], 1);
      atomicAdd(&cnt[d3 >> 7], 1);
    }
    for (; e < e1; e += 256) atomicAdd(&cnt[ei[E + e] >> 7], 1);
    __syncthreads();
    // LDS count -> absolute cursor (bucket region + block's reserved base)
    for (int j = threadIdx.x; j < nB; j += 256) {
      int c = cnt[j];
      int base = c ? atomicAdd(&gCnt[j], c) : 0;
      cnt[j] = j * cap + base;
    }
    __syncthreads();
    e = e0 + threadIdx.x;
    for (; e + 768 < e1; e += 1024) {
      int d0 = ei[E + e];
      int d1 = ei[E + e + 256];
      int d2 = ei[E + e + 512];
      int d3 = ei[E + e + 768];
      int s0 = ei[e];
      int s1 = ei[e + 256];
      int s2 = ei[e + 512];
      int s3 = ei[e + 768];
      int p0 = atomicAdd(&cnt[d0 >> 7], 1);
      int p1 = atomicAdd(&cnt[d1 >> 7], 1);
      int p2 = atomicAdd(&cnt[d2 >> 7], 1);
      int p3 = atomicAdd(&cnt[d3 >> 7], 1);
      ebuf[p0] = (unsigned)s0 | ((unsigned)(d0 & 127) << 16);
      ebuf[p1] = (unsigned)s1 | ((unsigned)(d1 & 127) << 16);
      ebuf[p2] = (unsigned)s2 | ((unsigned)(d2 & 127) << 16);
      ebuf[p3] = (unsigned)s3 | ((unsigned)(d3 & 127) << 16);
    }
    for (; e < e1; e += 256) {
      int dst = ei[E + e];
      int src = ei[e];
      int pos = atomicAdd(&cnt[dst >> 7], 1);
      ebuf[pos] = (unsigned)src | ((unsigned)(dst & 127) << 16);
    }
  } else {
    int gid = (blockIdx.x - NBKE) * 256 + threadIdx.x;
    if (gid < 32768) {  // Wt[n*128+k] = bf16(W[k*128+n])
      int sel = gid >> 14;
      int i = gid & 16383;
      int nn = i >> 7, k = i & 127;
      const float* W = sel ? Wr : Wl;
      unsigned short* Wt = sel ? Wrt : Wlt;
      Wt[i] = f2bf(W[k * HC + nn]);
    }
    if (gid >= cnt4) return;
    float4 v = ((const float4*)x)[gid];
    ushort4 o;
    o.x = f2bf(v.x); o.y = f2bf(v.y); o.z = f2bf(v.z); o.w = f2bf(v.w);
    ((ushort4*)xb)[gid] = o;
  }
}

// ========== K2: per-bucket CSR build (blocks < nB) ∥ layer-1 MFMA GEMM =======
__global__ __launch_bounds__(256) void csr_gemm1(
    const unsigned* __restrict__ ebuf, const int* __restrict__ gCnt, int cap,
    int* __restrict__ row_start, int* __restrict__ deg,
    int* __restrict__ csr_src, int N, int EPtot, int nB,
    const unsigned short* __restrict__ A,
    const unsigned short* __restrict__ Wlt, const unsigned short* __restrict__ Wrt,
    const float* __restrict__ bl, const float* __restrict__ br,
    unsigned short* __restrict__ xlb, unsigned short* __restrict__ xrb, int M) {
  if ((int)blockIdx.x < nB) {
    const int b = blockIdx.x;
    const int tid = threadIdx.x;
    __shared__ int red[256];
    __shared__ int degL[128], scanL[128], curL[128];
    // base = sum of bucket totals for k < b
    int s = 0;
    for (int k = tid; k < b; k += 256) s += gCnt[k];
    red[tid] = s;
    __syncthreads();
    for (int off = 128; off > 0; off >>= 1) {
      if (tid < off) red[tid] += red[tid + off];
      __syncthreads();
    }
    const int ebase = red[0];
    const int cnt = gCnt[b];
    const int node0 = b * 128;
    const int nb2 = (N - node0) < 128 ? (N - node0) : 128;
    const unsigned* eb = ebuf + (size_t)b * cap;
    if (tid < 128) degL[tid] = 0;
    __syncthreads();
    for (int e = tid; e < cnt; e += 256)
      atomicAdd(&degL[(eb[e] >> 16) & 127], 1);
    __syncthreads();
    if (tid < 128) scanL[tid] = degL[tid];
    __syncthreads();
    for (int off = 1; off < 128; off <<= 1) {
      int t = 0;
      if (tid < 128 && tid >= off) t = scanL[tid - off];
      __syncthreads();
      if (tid < 128) scanL[tid] += t;
      __syncthreads();
    }
    if (tid < 128) {
      int rs = ebase + (scanL[tid] - degL[tid]) + node0 + tid;  // + self-loop slots
      curL[tid] = rs;
      if (tid < nb2) {
        row_start[node0 + tid] = rs;
        deg[node0 + tid] = degL[tid];
      }
    }
    __syncthreads();
    for (int e = tid; e < cnt; e += 256) {
      unsigned p = eb[e];
      int pos = atomicAdd(&curL[(p >> 16) & 127], 1);
      csr_src[pos] = (int)(p & 0xffffu);
    }
    __syncthreads();
    if (tid < nb2) csr_src[curL[tid]] = node0 + tid;  // self-loop (final slot)
    if (b == 0 && tid < 32) csr_src[EPtot + tid] = 0;  // pad for unconditional SWP
  } else {
    const int row0 = (blockIdx.x - nB) * 32;
    if (row0 >= M) return;
    gemm32rows<128>(A, Wlt, Wrt, bl, br, xlb, xrb, M, row0, threadIdx.x);
  }
}

// ---------- layer-2 MFMA GEMM (standalone, 32-row blocks) ----------
template <int K>
__global__ __launch_bounds__(256) void gemm_mfma(
    const unsigned short* __restrict__ A,
    const unsigned short* __restrict__ Wlt, const unsigned short* __restrict__ Wrt,
    const float* __restrict__ bl, const float* __restrict__ br,
    unsigned short* __restrict__ xlb, unsigned short* __restrict__ xrb, int M) {
  const int row0 = blockIdx.x * 32;
  if (row0 >= M) return;
  gemm32rows<K>(A, Wlt, Wrt, bl, br, xlb, xrb, M, row0, threadIdx.x);
}

// ============ fused per-node attention (bf16 gather, 4 edges/iter, 3-deep SWP,
//   unconditional pipeline loads; DPP butterfly score reduce — no LDS ops) ====
__global__ __launch_bounds__(256) void node_attn(
    const unsigned short* __restrict__ xlb, const unsigned short* __restrict__ xrb,
    const int* __restrict__ csr_src, const int* __restrict__ row_start,
    const int* __restrict__ deg, const float* __restrict__ att,
    const float* __restrict__ bias, unsigned short* __restrict__ outb, int n) {
  int wave = (blockIdx.x * blockDim.x + threadIdx.x) >> 6;
  if (wave >= n) return;
  const int node = wave;
  const int lane = threadIdx.x & 63;
  const int g = lane >> 4;
  const int hl = lane & 15;
  const int c8 = hl << 3;  // flat channel base 0..120

  float r[8], a[8];
  {
    uint4 u = *(const uint4*)(xrb + (size_t)node * HC + c8);
    unpack8(u, r);
    float4 a0 = *(const float4*)(att + c8);
    float4 a1 = *(const float4*)(att + c8 + 4);
    // pre-fold log2(e) so the softmax exp is a bare v_exp_f32 (base-2 HW)
    const float L2E = 1.44269504f;
    a[0] = a0.x * L2E; a[1] = a0.y * L2E; a[2] = a0.z * L2E; a[3] = a0.w * L2E;
    a[4] = a1.x * L2E; a[5] = a1.y * L2E; a[6] = a1.z * L2E; a[7] = a1.w * L2E;
  }

  const int p0 = row_start[node];
  const int pend = p0 + deg[node] + 1;  // +1 self-loop

  float d = 0.f;
  float acc[8] = {0.f, 0.f, 0.f, 0.f, 0.f, 0.f, 0.f, 0.f};

  // 3-deep pipeline, UNCONDITIONAL loads (junk reads masked by w=0; array padded)
  int s0 = __builtin_nontemporal_load(csr_src + p0 + g);
  uint4 A0 = *(const uint4*)(xlb + (size_t)s0 * HC + c8);
  int s1 = __builtin_nontemporal_load(csr_src + p0 + 4 + g);
  uint4 A1 = *(const uint4*)(xlb + (size_t)s1 * HC + c8);
  int s2 = __builtin_nontemporal_load(csr_src + p0 + 8 + g);
  uint4 A2 = *(const uint4*)(xlb + (size_t)s2 * HC + c8);

  for (int p = p0; p < pend; p += 4) {
    int s3 = __builtin_nontemporal_load(csr_src + p + 12 + g);
    uint4 A3 = *(const uint4*)(xlb + (size_t)s3 * HC + c8);

    float v[8];
    unpack8(A0, v);
    float e1 = 0.f, e2 = 0.f;
#pragma unroll
    for (int i = 0; i < 8; i++) {
      float s = v[i] + r[i];
      e1 = fmaf(a[i], s, e1);
      e2 = fmaf(a[i], fabsf(s), e2);  // lrelu = 0.6t + 0.4|t|
    }
    float e = fmaf(0.4f, e2, 0.6f * e1);
    // 8-lane butterfly sum per head: full-rate VALU DPP (no ds_bpermute)
    e = dpp_add<0xB1>(e);   // quad_perm xor1
    e = dpp_add<0x4E>(e);   // quad_perm xor2
    e = dpp_add<0x141>(e);  // row_half_mirror (xor4 after 1,2 folds)

    bool valid = (p + g) < pend;
    float w = valid ? exp2f(e) : 0.f;
    d += w;
#pragma unroll
    for (int i = 0; i < 8; i++) acc[i] = fmaf(w, v[i], acc[i]);
    A0 = A1; A1 = A2; A2 = A3;
  }

#pragma unroll
  for (int ofs = 16; ofs <= 32; ofs <<= 1) {
    d += __shfl_xor(d, ofs);
#pragma unroll
    for (int i = 0; i < 8; i++) acc[i] += __shfl_xor(acc[i], ofs);
  }
  float inv = 1.f / (d + 1e-16f);
  const float* bb = bias + (c8 & 63);
  float o[8];
#pragma unroll
  for (int i = 0; i < 8; i++) {
    float t = acc[i] * inv;
    float t2 = __shfl_xor(t, 8);  // other head, same output channel
    o[i] = 0.5f * (t + t2) + bb[i];
  }
  if (lane < 8) {
    uint4 ou;
    ou.x = (unsigned)f2bf(o[0]) | ((unsigned)f2bf(o[1]) << 16);
    ou.y = (unsigned)f2bf(o[2]) | ((unsigned)f2bf(o[3]) << 16);
    ou.z = (unsigned)f2bf(o[4]) | ((unsigned)f2bf(o[5]) << 16);
    ou.w = (unsigned)f2bf(o[6]) | ((unsigned)f2bf(o[7]) << 16);
    *(uint4*)(outb + (size_t)node * CCH + c8) = ou;
  }
}

// ====== GraphNorm stats, atomic-free: uint4 loads -> wave shfl reduce ->
//   LDS cross-wave reduce -> per-block partials -> last block PARALLEL sum ====
__device__ __forceinline__ int gn_stats_core(
    const unsigned short* __restrict__ y, float* __restrict__ partial,
    float* __restrict__ S, int* __restrict__ done, int n) {
  const int tid = threadIdx.x;
  const int lane = tid & 63, wv = tid >> 6;
  const int chunk = lane & 7, rowoff = lane >> 3;
  float s1[8] = {0.f, 0.f, 0.f, 0.f, 0.f, 0.f, 0.f, 0.f};
  float s2[8] = {0.f, 0.f, 0.f, 0.f, 0.f, 0.f, 0.f, 0.f};
  const int stride = GSTB * 32;
  for (int r = blockIdx.x * 32 + wv * 8 + rowoff; r < n; r += stride) {
    uint4 u = ((const uint4*)(y + (size_t)r * CCH))[chunk];
    float f[8];
    unpack8(u, f);
#pragma unroll
    for (int j = 0; j < 8; j++) {
      s1[j] += f[j];
      s2[j] = fmaf(f[j], f[j], s2[j]);
    }
  }
  // butterfly over rowoff (lane bits 3..5)
#pragma unroll
  for (int ofs = 8; ofs <= 32; ofs <<= 1) {
#pragma unroll
    for (int j = 0; j < 8; j++) {
      s1[j] += __shfl_xor(s1[j], ofs);
      s2[j] += __shfl_xor(s2[j], ofs);
    }
  }
  __shared__ float lds[4][8][16];
  if (rowoff == 0) {
#pragma unroll
    for (int j = 0; j < 8; j++) {
      lds[wv][chunk][j] = s1[j];
      lds[wv][chunk][8 + j] = s2[j];
    }
  }
  __syncthreads();
  if (tid < 128) {
    int ch = tid & 63, st = tid >> 6;  // st: 0=sum, 1=sumsq
    int ck = ch >> 3, j = (ch & 7) + st * 8;
    float v = lds[0][ck][j] + lds[1][ck][j] + lds[2][ck][j] + lds[3][ck][j];
    partial[blockIdx.x * 128 + st * 64 + ch] = v;
  }
  __threadfence();
  __shared__ int isLast;
  if (tid == 0) isLast = (atomicAdd(done, 1) == GSTB - 1) ? 1 : 0;
  __syncthreads();
  if (!isLast) return 0;
  __threadfence();
  // parallel tail: 256 threads = 2 halves x 128 channels, unrolled indep loads
  __shared__ float sumL[2][128];
  {
    int ch = tid & 127, half = tid >> 7;
    const float* p = partial + (size_t)half * (GSTB / 2) * 128 + ch;
    float v = 0.f;
#pragma unroll
    for (int b = 0; b < GSTB / 2; b++) v += p[b * 128];
    sumL[half][ch] = v;
  }
  __syncthreads();
  if (tid < 128) S[tid] = sumL[0][tid] + sumL[1][tid];
  __syncthreads();
  return 1;
}

__global__ __launch_bounds__(256) void gn_stats(
    const unsigned short* __restrict__ y, float* __restrict__ partial,
    float* __restrict__ S, int* __restrict__ done, int n) {
  gn_stats_core(y, partial, S, done, n);
}

// ---------- GraphNorm-1 stats + weight fold (last block folds) ----------
__global__ __launch_bounds__(256) void gn_stats_prep(
    const unsigned short* __restrict__ y, float* __restrict__ partial,
    float* __restrict__ S, int* __restrict__ done,
    const float* __restrict__ gamma, const float* __restrict__ beta,
    const float* __restrict__ mscale,
    const float* __restrict__ Wl2, const float* __restrict__ bl2,
    const float* __restrict__ Wr2, const float* __restrict__ br2,
    unsigned short* __restrict__ Wl2tb, float* __restrict__ bl2p,
    unsigned short* __restrict__ Wr2tb, float* __restrict__ br2p, int n) {
  if (!gn_stats_core(y, partial, S, done, n)) return;
  __shared__ float As[64], Bs[64];
  int t = threadIdx.x;
  if (t < 64) {
    float invn = 1.f / (float)n;
    float mu = S[t] * invn;
    float ms = mscale[t];
    float var = S[64 + t] * invn - 2.f * ms * mu * mu + ms * ms * mu * mu;
    float A = gamma[t] * rsqrtf(var + 1e-5f);
    As[t] = A;
    Bs[t] = beta[t] - A * ms * mu;
  }
  __syncthreads();
  const int side = t >> 7, col = t & 127;
  const float* W = side ? Wr2 : Wl2;
  unsigned short* Wt = side ? Wr2tb : Wl2tb;
  const float* bin = side ? br2 : bl2;
  float* bout = side ? br2p : bl2p;
  float s = 0.f;
#pragma unroll
  for (int c = 0; c < 64; c++) {
    float w = W[c * HC + col];
    Wt[col * 64 + c] = f2bf(As[c] * w);
    s = fmaf(Bs[c], w, s);
  }
  bout[col] = bin[col] + s;
}

// ---------- classifier + log_softmax, GraphNorm-2 folded in-block ----------
__global__ __launch_bounds__(256) void classify(
    const unsigned short* __restrict__ h,
    const float* __restrict__ S, const float* __restrict__ gamma,
    const float* __restrict__ beta, const float* __restrict__ mscale,
    const float* __restrict__ W, const float* __restrict__ b,
    float* __restrict__ out, int n) {
  __shared__ float4 sW[64];
  __shared__ float sBt[256];
  __shared__ float sb[4];
  int tid = threadIdx.x;
  if (tid < 64) {
    float invn = 1.f / (float)n;
    float mu = S[tid] * invn;
    float ms = mscale[tid];
    float var = S[64 + tid] * invn - 2.f * ms * mu * mu + ms * ms * mu * mu;
    float A = gamma[tid] * rsqrtf(var + 1e-5f);
    float B = beta[tid] - A * ms * mu;
    float4 w = ((const float4*)W)[tid];
    sW[tid] = make_float4(A * w.x, A * w.y, A * w.z, A * w.w);
    sBt[tid * 4 + 0] = B * w.x; sBt[tid * 4 + 1] = B * w.y;
    sBt[tid * 4 + 2] = B * w.z; sBt[tid * 4 + 3] = B * w.w;
  }
  __syncthreads();
  if (tid < 4) {
    float s = b[tid];
    for (int c = 0; c < 64; c++) s += sBt[c * 4 + tid];
    sb[tid] = s;
  }
  __syncthreads();
  int node = blockIdx.x * 256 + tid;
  if (node >= n) return;
  float acc0 = sb[0], acc1 = sb[1], acc2 = sb[2], acc3 = sb[3];
  const uint4* row = (const uint4*)(h + (size_t)node * CCH);
#pragma unroll
  for (int k4 = 0; k4 < 8; k4++) {
    uint4 u = row[k4];
    float v[8];
    unpack8(u, v);
#pragma unroll
    for (int j = 0; j < 8; j++) {
      float4 w = sW[k4 * 8 + j];
      acc0 = fmaf(v[j], w.x, acc0);
      acc1 = fmaf(v[j], w.y, acc1);
      acc2 = fmaf(v[j], w.z, acc2);
      acc3 = fmaf(v[j], w.w, acc3);
    }
  }
  float mx = fmaxf(fmaxf(acc0, acc1), fmaxf(acc2, acc3));
  float s = __expf(acc0 - mx) + __expf(acc1 - mx) + __expf(acc2 - mx) + __expf(acc3 - mx);
  float lse = mx + logf(s);
  float4 o = make_float4(acc0 - lse, acc1 - lse, acc2 - lse, acc3 - lse);
  *((float4*)(out + (size_t)node * 4)) = o;
}

extern "C" void kernel_launch(void* const* d_in, const int* in_sizes, int n_in,
                              void* d_out, int out_size, void* d_ws, size_t ws_size,
                              hipStream_t stream) {
  const float* x     = (const float*)d_in[0];
  const int*   ei    = (const int*)d_in[1];
  const float* Wl1   = (const float*)d_in[2];
  const float* bl1   = (const float*)d_in[3];
  const float* Wr1   = (const float*)d_in[4];
  const float* br1   = (const float*)d_in[5];
  const float* att1  = (const float*)d_in[6];
  const float* bias1 = (const float*)d_in[7];
  const float* gng1  = (const float*)d_in[8];
  const float* gnb1  = (const float*)d_in[9];
  const float* gna1  = (const float*)d_in[10];
  const float* Wl2   = (const float*)d_in[11];
  const float* bl2   = (const float*)d_in[12];
  const float* Wr2   = (const float*)d_in[13];
  const float* br2   = (const float*)d_in[14];
  const float* att2  = (const float*)d_in[15];
  const float* bias2 = (const float*)d_in[16];
  const float* gng2  = (const float*)d_in[17];
  const float* gnb2  = (const float*)d_in[18];
  const float* gna2  = (const float*)d_in[19];
  const float* W1    = (const float*)d_in[20];
  const float* b1    = (const float*)d_in[21];

  const int N = in_sizes[0] / 128;
  const int E = in_sizes[1] / 2;
  const int EP = E + N;
  const int nB = (N + 127) >> 7;            // dst-buckets of 128 nodes
  const int chunk = (E + NBKE - 1) / NBKE;  // edges per binning block
  const int cap = ((E / nB) * 2 + 255) & ~255;  // strided ebuf capacity (+~22 sigma)

  // workspace layout: zeroed header [gCnt | S1 | S2 | done] first
  int* gCnt = (int*)d_ws;                        // 512 (bucket totals)
  float* S1  = (float*)(gCnt + 512);             // 128
  float* S2  = S1 + 128;                         // 128
  int* done  = (int*)(S2 + 128);                 // 64 (2 used)
  float* bl2p = (float*)(done + 64);             // 128
  float* br2p = bl2p + 128;                      // 128
  float* part1 = br2p + 128;                     // GSTB*128
  float* part2 = part1 + GSTB * 128;             // GSTB*128
  unsigned short* xb    = (unsigned short*)(part2 + GSTB * 128);  // N*128
  unsigned short* xlb   = xb + (size_t)N * HC;            // N*128
  unsigned short* xrb   = xlb + (size_t)N * HC;           // N*128
  unsigned short* aggb  = xrb + (size_t)N * HC;           // N*64
  unsigned short* Wl1tb = aggb + (size_t)N * CCH;         // 128*128
  unsigned short* Wr1tb = Wl1tb + HC * HC;                // 128*128
  unsigned short* Wl2tb = Wr1tb + HC * HC;                // 128*64
  unsigned short* Wr2tb = Wl2tb + HC * CCH;               // 128*64
  int* row_st  = (int*)(Wr2tb + HC * CCH);                // N
  int* deg     = row_st + N;                              // N
  unsigned* ebuf = (unsigned*)(deg + N);                  // nB*cap (strided)
  int* csr_src = (int*)(ebuf + (size_t)nB * cap);         // EP + 64 pad

  dim3 b256(256);
  const int gNode = (N * 64 + 255) / 256;
  const int gCls  = (N + 255) / 256;
  const int gCast = (N * 32 + 255) / 256;
  const int gGemm = (N + 31) / 32;

  // ---- zero header (gCnt + S1 + S2 + done) ----
  hipMemsetAsync(d_ws, 0, 4096, stream);

  // ---- K1: fused multisplit count+place ∥ casts ----
  binplace_cast<<<NBKE + gCast, b256, 0, stream>>>(
      ei, E, chunk, nB, cap, gCnt, ebuf,
      x, xb, N * 32, Wl1, Wr1, Wl1tb, Wr1tb);

  // ---- K2: per-bucket CSR build ∥ layer-1 GEMM ----
  csr_gemm1<<<nB + gGemm, b256, 0, stream>>>(
      ebuf, gCnt, cap, row_st, deg, csr_src, N, EP, nB,
      xb, Wl1tb, Wr1tb, bl1, br1, xlb, xrb, N);

  // ---- Layer 1 attention + fused stats/weight-fold (parallel tail) ----
  node_attn<<<gNode, b256, 0, stream>>>(xlb, xrb, csr_src, row_st, deg, att1, bias1, aggb, N);
  gn_stats_prep<<<GSTB, b256, 0, stream>>>(aggb, part1, S1, done, gng1, gnb1, gna1,
                                           Wl2, bl2, Wr2, br2,
                                           Wl2tb, bl2p, Wr2tb, br2p, N);

  // ---- Layer 2 ----
  gemm_mfma<64><<<gGemm, b256, 0, stream>>>(aggb, Wl2tb, Wr2tb, bl2p, br2p, xlb, xrb, N);
  node_attn<<<gNode, b256, 0, stream>>>(xlb, xrb, csr_src, row_st, deg, att2, bias2, aggb, N);
  gn_stats<<<GSTB, b256, 0, stream>>>(aggb, part2, S2, done + 1, N);

  // ---- Classifier (GraphNorm-2 folded in-block) ----
  classify<<<gCls, b256, 0, stream>>>(aggb, S2, gng2, gnb2, gna2, W1, b1,
                                      (float*)d_out, N);
}

// Round 14
// 295.108 us; speedup vs baseline: 1.0292x; 1.0292x over previous
//
#include <hip/hip_runtime.h>
#include <hip/hip_bf16.h>
#include <math.h>

// Sizes per reference: DIN=128, H=2, C=64, H*C=128, NUM_CLASSES=4
// NOTE: packing below requires N < 65536 (harness: N=50000).
#define HC   128
#define CCH  64
#define NBKE 256   // edge-processing blocks in fused bin+place (1 per CU; r13's 512 regressed)
#define GSTB 128   // stats blocks (atomic-free partials; compile-time for unroll)

typedef __attribute__((ext_vector_type(8))) short short8;
typedef __attribute__((ext_vector_type(4))) float floatx4;

__device__ __forceinline__ unsigned short f2bf(float f) {
  unsigned u = __float_as_uint(f);
  u += 0x7fffu + ((u >> 16) & 1u);  // RNE
  return (unsigned short)(u >> 16);
}

__device__ __forceinline__ void unpack8(uint4 u, float* f) {
  f[0] = __uint_as_float(u.x << 16);
  f[1] = __uint_as_float(u.x & 0xffff0000u);
  f[2] = __uint_as_float(u.y << 16);
  f[3] = __uint_as_float(u.y & 0xffff0000u);
  f[4] = __uint_as_float(u.z << 16);
  f[5] = __uint_as_float(u.z & 0xffff0000u);
  f[6] = __uint_as_float(u.w << 16);
  f[7] = __uint_as_float(u.w & 0xffff0000u);
}

// full-rate VALU lane-sum step: x += lane[ctrl-permuted x] (no LDS, no waitcnt)
template <int CTRL>
__device__ __forceinline__ float dpp_add(float x) {
  int t = __builtin_amdgcn_update_dpp(0, __float_as_int(x), CTRL, 0xf, 0xf, true);
  return x + __int_as_float(t);
}

// 32-row dual-side GEMM tile: 4 waves = {L,R} x {cols 0-63, 64-127},
// each wave does 2 row-groups of 16 against the SAME B registers
// (8 independent MFMAs per k-step, 0.75 loads/MFMA). Verified r1-r12.
template <int K>
__device__ __forceinline__ void gemm32rows(
    const unsigned short* __restrict__ A,
    const unsigned short* __restrict__ Wlt, const unsigned short* __restrict__ Wrt,
    const float* __restrict__ bl, const float* __restrict__ br,
    unsigned short* __restrict__ xlb, unsigned short* __restrict__ xrb,
    int M, int row0, int tid) {
  const int w = tid >> 6;
  const int lane = tid & 63;
  const bool isR = w >= 2;
  const unsigned short* Wt = isR ? Wrt : Wlt;
  const float* bias = isR ? br : bl;
  unsigned short* out = isR ? xrb : xlb;
  const int col0 = (w & 1) * 64;
  const int mrow = lane & 15, quad = lane >> 4;
  const unsigned short* pa0 = A + (size_t)(row0 + mrow) * K + quad * 8;
  const unsigned short* pa1 = pa0 + (size_t)16 * K;
  const unsigned short* pb = Wt + (size_t)(col0 + mrow) * K + quad * 8;
  floatx4 acc[2][4];
#pragma unroll
  for (int gp = 0; gp < 2; gp++)
#pragma unroll
    for (int ct = 0; ct < 4; ct++) acc[gp][ct] = (floatx4){0.f, 0.f, 0.f, 0.f};
#pragma unroll
  for (int k0 = 0; k0 < K; k0 += 32) {
    short8 a0 = *(const short8*)(pa0 + k0);
    short8 a1 = *(const short8*)(pa1 + k0);
    short8 b0 = *(const short8*)(pb + k0);
    short8 b1 = *(const short8*)(pb + 16 * K + k0);
    short8 b2 = *(const short8*)(pb + 32 * K + k0);
    short8 b3 = *(const short8*)(pb + 48 * K + k0);
    acc[0][0] = __builtin_amdgcn_mfma_f32_16x16x32_bf16(a0, b0, acc[0][0], 0, 0, 0);
    acc[1][0] = __builtin_amdgcn_mfma_f32_16x16x32_bf16(a1, b0, acc[1][0], 0, 0, 0);
    acc[0][1] = __builtin_amdgcn_mfma_f32_16x16x32_bf16(a0, b1, acc[0][1], 0, 0, 0);
    acc[1][1] = __builtin_amdgcn_mfma_f32_16x16x32_bf16(a1, b1, acc[1][1], 0, 0, 0);
    acc[0][2] = __builtin_amdgcn_mfma_f32_16x16x32_bf16(a0, b2, acc[0][2], 0, 0, 0);
    acc[1][2] = __builtin_amdgcn_mfma_f32_16x16x32_bf16(a1, b2, acc[1][2], 0, 0, 0);
    acc[0][3] = __builtin_amdgcn_mfma_f32_16x16x32_bf16(a0, b3, acc[0][3], 0, 0, 0);
    acc[1][3] = __builtin_amdgcn_mfma_f32_16x16x32_bf16(a1, b3, acc[1][3], 0, 0, 0);
  }
#pragma unroll
  for (int gp = 0; gp < 2; gp++) {
#pragma unroll
    for (int ct = 0; ct < 4; ct++) {
      int col = col0 + ct * 16 + mrow;
      float bv = bias[col];
#pragma unroll
      for (int r = 0; r < 4; r++) {
        int row = row0 + gp * 16 + quad * 4 + r;
        if (row < M) out[(size_t)row * HC + col] = f2bf(acc[gp][ct][r] + bv);
      }
    }
  }
}

// ========== K1: fused multisplit count+place (blocks < NBKE) ∥ casts =========
__global__ __launch_bounds__(256) void binplace_cast(
    const int* __restrict__ ei, int E, int chunk, int nB, int cap,
    int* __restrict__ gCnt, unsigned* __restrict__ ebuf,
    const float* __restrict__ x, unsigned short* __restrict__ xb, int cnt4,
    const float* __restrict__ Wl, const float* __restrict__ Wr,
    unsigned short* __restrict__ Wlt, unsigned short* __restrict__ Wrt) {
  if ((int)blockIdx.x < NBKE) {
    __shared__ int cnt[512];
    for (int j = threadIdx.x; j < nB; j += 256) cnt[j] = 0;
    __syncthreads();
    int e0 = blockIdx.x * chunk;
    int e1 = e0 + chunk; e1 = e1 < E ? e1 : E;
    int e = e0 + threadIdx.x;
    for (; e + 768 < e1; e += 1024) {
      int d0 = ei[E + e];
      int d1 = ei[E + e + 256];
      int d2 = ei[E + e + 512];
      int d3 = ei[E + e + 768];
      atomicAdd(&cnt[d0 >> 7], 1);
      atomicAdd(&cnt[d1 >> 7], 1);
      atomicAdd(&cnt[d2 >> 7], 1);
      atomicAdd(&cnt[d3 >> 7], 1);
    }
    for (; e < e1; e += 256) atomicAdd(&cnt[ei[E + e] >> 7], 1);
    __syncthreads();
    // LDS count -> absolute cursor (bucket region + block's reserved base)
    for (int j = threadIdx.x; j < nB; j += 256) {
      int c = cnt[j];
      int base = c ? atomicAdd(&gCnt[j], c) : 0;
      cnt[j] = j * cap + base;
    }
    __syncthreads();
    e = e0 + threadIdx.x;
    for (; e + 768 < e1; e += 1024) {
      int d0 = ei[E + e];
      int d1 = ei[E + e + 256];
      int d2 = ei[E + e + 512];
      int d3 = ei[E + e + 768];
      int s0 = ei[e];
      int s1 = ei[e + 256];
      int s2 = ei[e + 512];
      int s3 = ei[e + 768];
      int p0 = atomicAdd(&cnt[d0 >> 7], 1);
      int p1 = atomicAdd(&cnt[d1 >> 7], 1);
      int p2 = atomicAdd(&cnt[d2 >> 7], 1);
      int p3 = atomicAdd(&cnt[d3 >> 7], 1);
      ebuf[p0] = (unsigned)s0 | ((unsigned)(d0 & 127) << 16);
      ebuf[p1] = (unsigned)s1 | ((unsigned)(d1 & 127) << 16);
      ebuf[p2] = (unsigned)s2 | ((unsigned)(d2 & 127) << 16);
      ebuf[p3] = (unsigned)s3 | ((unsigned)(d3 & 127) << 16);
    }
    for (; e < e1; e += 256) {
      int dst = ei[E + e];
      int src = ei[e];
      int pos = atomicAdd(&cnt[dst >> 7], 1);
      ebuf[pos] = (unsigned)src | ((unsigned)(dst & 127) << 16);
    }
  } else {
    int gid = (blockIdx.x - NBKE) * 256 + threadIdx.x;
    if (gid < 32768) {  // Wt[n*128+k] = bf16(W[k*128+n])
      int sel = gid >> 14;
      int i = gid & 16383;
      int nn = i >> 7, k = i & 127;
      const float* W = sel ? Wr : Wl;
      unsigned short* Wt = sel ? Wrt : Wlt;
      Wt[i] = f2bf(W[k * HC + nn]);
    }
    if (gid >= cnt4) return;
    float4 v = ((const float4*)x)[gid];
    ushort4 o;
    o.x = f2bf(v.x); o.y = f2bf(v.y); o.z = f2bf(v.z); o.w = f2bf(v.w);
    ((ushort4*)xb)[gid] = o;
  }
}

// ========== K2: per-bucket CSR build (blocks < nB) ∥ layer-1 MFMA GEMM =======
__global__ __launch_bounds__(256) void csr_gemm1(
    const unsigned* __restrict__ ebuf, const int* __restrict__ gCnt, int cap,
    int* __restrict__ row_start, int* __restrict__ deg,
    int* __restrict__ csr_src, int N, int EPtot, int nB,
    const unsigned short* __restrict__ A,
    const unsigned short* __restrict__ Wlt, const unsigned short* __restrict__ Wrt,
    const float* __restrict__ bl, const float* __restrict__ br,
    unsigned short* __restrict__ xlb, unsigned short* __restrict__ xrb, int M) {
  if ((int)blockIdx.x < nB) {
    const int b = blockIdx.x;
    const int tid = threadIdx.x;
    __shared__ int red[256];
    __shared__ int degL[128], scanL[128], curL[128];
    // base = sum of bucket totals for k < b
    int s = 0;
    for (int k = tid; k < b; k += 256) s += gCnt[k];
    red[tid] = s;
    __syncthreads();
    for (int off = 128; off > 0; off >>= 1) {
      if (tid < off) red[tid] += red[tid + off];
      __syncthreads();
    }
    const int ebase = red[0];
    const int cnt = gCnt[b];
    const int node0 = b * 128;
    const int nb2 = (N - node0) < 128 ? (N - node0) : 128;
    const unsigned* eb = ebuf + (size_t)b * cap;
    if (tid < 128) degL[tid] = 0;
    __syncthreads();
    for (int e = tid; e < cnt; e += 256)
      atomicAdd(&degL[(eb[e] >> 16) & 127], 1);
    __syncthreads();
    if (tid < 128) scanL[tid] = degL[tid];
    __syncthreads();
    for (int off = 1; off < 128; off <<= 1) {
      int t = 0;
      if (tid < 128 && tid >= off) t = scanL[tid - off];
      __syncthreads();
      if (tid < 128) scanL[tid] += t;
      __syncthreads();
    }
    if (tid < 128) {
      int rs = ebase + (scanL[tid] - degL[tid]) + node0 + tid;  // + self-loop slots
      curL[tid] = rs;
      if (tid < nb2) {
        row_start[node0 + tid] = rs;
        deg[node0 + tid] = degL[tid];
      }
    }
    __syncthreads();
    for (int e = tid; e < cnt; e += 256) {
      unsigned p = eb[e];
      int pos = atomicAdd(&curL[(p >> 16) & 127], 1);
      csr_src[pos] = (int)(p & 0xffffu);
    }
    __syncthreads();
    if (tid < nb2) csr_src[curL[tid]] = node0 + tid;  // self-loop (final slot)
    if (b == 0 && tid < 32) csr_src[EPtot + tid] = 0;  // pad for unconditional SWP
  } else {
    const int row0 = (blockIdx.x - nB) * 32;
    if (row0 >= M) return;
    gemm32rows<128>(A, Wlt, Wrt, bl, br, xlb, xrb, M, row0, threadIdx.x);
  }
}

// ---------- layer-2 MFMA GEMM (standalone, 32-row blocks) ----------
template <int K>
__global__ __launch_bounds__(256) void gemm_mfma(
    const unsigned short* __restrict__ A,
    const unsigned short* __restrict__ Wlt, const unsigned short* __restrict__ Wrt,
    const float* __restrict__ bl, const float* __restrict__ br,
    unsigned short* __restrict__ xlb, unsigned short* __restrict__ xrb, int M) {
  const int row0 = blockIdx.x * 32;
  if (row0 >= M) return;
  gemm32rows<K>(A, Wlt, Wrt, bl, br, xlb, xrb, M, row0, threadIdx.x);
}

// ============ fused per-node attention (bf16 gather, 4 edges/iter, 3-deep SWP,
//   unconditional pipeline loads; DPP butterfly score reduce — no LDS ops) ====
__global__ __launch_bounds__(256) void node_attn(
    const unsigned short* __restrict__ xlb, const unsigned short* __restrict__ xrb,
    const int* __restrict__ csr_src, const int* __restrict__ row_start,
    const int* __restrict__ deg, const float* __restrict__ att,
    const float* __restrict__ bias, unsigned short* __restrict__ outb, int n) {
  int wave = (blockIdx.x * blockDim.x + threadIdx.x) >> 6;
  if (wave >= n) return;
  const int node = wave;
  const int lane = threadIdx.x & 63;
  const int g = lane >> 4;
  const int hl = lane & 15;
  const int c8 = hl << 3;  // flat channel base 0..120

  float r[8], a[8];
  {
    uint4 u = *(const uint4*)(xrb + (size_t)node * HC + c8);
    unpack8(u, r);
    float4 a0 = *(const float4*)(att + c8);
    float4 a1 = *(const float4*)(att + c8 + 4);
    // pre-fold log2(e) so the softmax exp is a bare v_exp_f32 (base-2 HW)
    const float L2E = 1.44269504f;
    a[0] = a0.x * L2E; a[1] = a0.y * L2E; a[2] = a0.z * L2E; a[3] = a0.w * L2E;
    a[4] = a1.x * L2E; a[5] = a1.y * L2E; a[6] = a1.z * L2E; a[7] = a1.w * L2E;
  }

  const int p0 = row_start[node];
  const int pend = p0 + deg[node] + 1;  // +1 self-loop

  float d = 0.f;
  float acc[8] = {0.f, 0.f, 0.f, 0.f, 0.f, 0.f, 0.f, 0.f};

  // 3-deep pipeline, UNCONDITIONAL loads (junk reads masked by w=0; array padded)
  int s0 = __builtin_nontemporal_load(csr_src + p0 + g);
  uint4 A0 = *(const uint4*)(xlb + (size_t)s0 * HC + c8);
  int s1 = __builtin_nontemporal_load(csr_src + p0 + 4 + g);
  uint4 A1 = *(const uint4*)(xlb + (size_t)s1 * HC + c8);
  int s2 = __builtin_nontemporal_load(csr_src + p0 + 8 + g);
  uint4 A2 = *(const uint4*)(xlb + (size_t)s2 * HC + c8);

  for (int p = p0; p < pend; p += 4) {
    int s3 = __builtin_nontemporal_load(csr_src + p + 12 + g);
    uint4 A3 = *(const uint4*)(xlb + (size_t)s3 * HC + c8);

    float v[8];
    unpack8(A0, v);
    float e1 = 0.f, e2 = 0.f;
#pragma unroll
    for (int i = 0; i < 8; i++) {
      float s = v[i] + r[i];
      e1 = fmaf(a[i], s, e1);
      e2 = fmaf(a[i], fabsf(s), e2);  // lrelu = 0.6t + 0.4|t|
    }
    float e = fmaf(0.4f, e2, 0.6f * e1);
    // 8-lane butterfly sum per head: full-rate VALU DPP (no ds_bpermute)
    e = dpp_add<0xB1>(e);   // quad_perm xor1
    e = dpp_add<0x4E>(e);   // quad_perm xor2
    e = dpp_add<0x141>(e);  // row_half_mirror (xor4 after 1,2 folds)

    bool valid = (p + g) < pend;
    float w = valid ? exp2f(e) : 0.f;
    d += w;
#pragma unroll
    for (int i = 0; i < 8; i++) acc[i] = fmaf(w, v[i], acc[i]);
    A0 = A1; A1 = A2; A2 = A3;
  }

#pragma unroll
  for (int ofs = 16; ofs <= 32; ofs <<= 1) {
    d += __shfl_xor(d, ofs);
#pragma unroll
    for (int i = 0; i < 8; i++) acc[i] += __shfl_xor(acc[i], ofs);
  }
  float inv = 1.f / (d + 1e-16f);
  const float* bb = bias + (c8 & 63);
  float o[8];
#pragma unroll
  for (int i = 0; i < 8; i++) {
    float t = acc[i] * inv;
    float t2 = __shfl_xor(t, 8);  // other head, same output channel
    o[i] = 0.5f * (t + t2) + bb[i];
  }
  if (lane < 8) {
    uint4 ou;
    ou.x = (unsigned)f2bf(o[0]) | ((unsigned)f2bf(o[1]) << 16);
    ou.y = (unsigned)f2bf(o[2]) | ((unsigned)f2bf(o[3]) << 16);
    ou.z = (unsigned)f2bf(o[4]) | ((unsigned)f2bf(o[5]) << 16);
    ou.w = (unsigned)f2bf(o[6]) | ((unsigned)f2bf(o[7]) << 16);
    *(uint4*)(outb + (size_t)node * CCH + c8) = ou;
  }
}

// ====== GraphNorm stats, atomic-free: uint4 loads -> wave shfl reduce ->
//   LDS cross-wave reduce -> per-block partials -> last block PARALLEL sum ====
__device__ __forceinline__ int gn_stats_core(
    const unsigned short* __restrict__ y, float* __restrict__ partial,
    float* __restrict__ S, int* __restrict__ done, int n) {
  const int tid = threadIdx.x;
  const int lane = tid & 63, wv = tid >> 6;
  const int chunk = lane & 7, rowoff = lane >> 3;
  float s1[8] = {0.f, 0.f, 0.f, 0.f, 0.f, 0.f, 0.f, 0.f};
  float s2[8] = {0.f, 0.f, 0.f, 0.f, 0.f, 0.f, 0.f, 0.f};
  const int stride = GSTB * 32;
  for (int r = blockIdx.x * 32 + wv * 8 + rowoff; r < n; r += stride) {
    uint4 u = ((const uint4*)(y + (size_t)r * CCH))[chunk];
    float f[8];
    unpack8(u, f);
#pragma unroll
    for (int j = 0; j < 8; j++) {
      s1[j] += f[j];
      s2[j] = fmaf(f[j], f[j], s2[j]);
    }
  }
  // butterfly over rowoff (lane bits 3..5)
#pragma unroll
  for (int ofs = 8; ofs <= 32; ofs <<= 1) {
#pragma unroll
    for (int j = 0; j < 8; j++) {
      s1[j] += __shfl_xor(s1[j], ofs);
      s2[j] += __shfl_xor(s2[j], ofs);
    }
  }
  __shared__ float lds[4][8][16];
  if (rowoff == 0) {
#pragma unroll
    for (int j = 0; j < 8; j++) {
      lds[wv][chunk][j] = s1[j];
      lds[wv][chunk][8 + j] = s2[j];
    }
  }
  __syncthreads();
  if (tid < 128) {
    int ch = tid & 63, st = tid >> 6;  // st: 0=sum, 1=sumsq
    int ck = ch >> 3, j = (ch & 7) + st * 8;
    float v = lds[0][ck][j] + lds[1][ck][j] + lds[2][ck][j] + lds[3][ck][j];
    partial[blockIdx.x * 128 + st * 64 + ch] = v;
  }
  __threadfence();
  __shared__ int isLast;
  if (tid == 0) isLast = (atomicAdd(done, 1) == GSTB - 1) ? 1 : 0;
  __syncthreads();
  if (!isLast) return 0;
  __threadfence();
  // parallel tail: 256 threads = 2 halves x 128 channels, unrolled indep loads
  __shared__ float sumL[2][128];
  {
    int ch = tid & 127, half = tid >> 7;
    const float* p = partial + (size_t)half * (GSTB / 2) * 128 + ch;
    float v = 0.f;
#pragma unroll
    for (int b = 0; b < GSTB / 2; b++) v += p[b * 128];
    sumL[half][ch] = v;
  }
  __syncthreads();
  if (tid < 128) S[tid] = sumL[0][tid] + sumL[1][tid];
  __syncthreads();
  return 1;
}

__global__ __launch_bounds__(256) void gn_stats(
    const unsigned short* __restrict__ y, float* __restrict__ partial,
    float* __restrict__ S, int* __restrict__ done, int n) {
  gn_stats_core(y, partial, S, done, n);
}

// ---------- GraphNorm-1 stats + weight fold (last block folds) ----------
__global__ __launch_bounds__(256) void gn_stats_prep(
    const unsigned short* __restrict__ y, float* __restrict__ partial,
    float* __restrict__ S, int* __restrict__ done,
    const float* __restrict__ gamma, const float* __restrict__ beta,
    const float* __restrict__ mscale,
    const float* __restrict__ Wl2, const float* __restrict__ bl2,
    const float* __restrict__ Wr2, const float* __restrict__ br2,
    unsigned short* __restrict__ Wl2tb, float* __restrict__ bl2p,
    unsigned short* __restrict__ Wr2tb, float* __restrict__ br2p, int n) {
  if (!gn_stats_core(y, partial, S, done, n)) return;
  __shared__ float As[64], Bs[64];
  int t = threadIdx.x;
  if (t < 64) {
    float invn = 1.f / (float)n;
    float mu = S[t] * invn;
    float ms = mscale[t];
    float var = S[64 + t] * invn - 2.f * ms * mu * mu + ms * ms * mu * mu;
    float A = gamma[t] * rsqrtf(var + 1e-5f);
    As[t] = A;
    Bs[t] = beta[t] - A * ms * mu;
  }
  __syncthreads();
  const int side = t >> 7, col = t & 127;
  const float* W = side ? Wr2 : Wl2;
  unsigned short* Wt = side ? Wr2tb : Wl2tb;
  const float* bin = side ? br2 : bl2;
  float* bout = side ? br2p : bl2p;
  float s = 0.f;
#pragma unroll
  for (int c = 0; c < 64; c++) {
    float w = W[c * HC + col];
    Wt[col * 64 + c] = f2bf(As[c] * w);
    s = fmaf(Bs[c], w, s);
  }
  bout[col] = bin[col] + s;
}

// ---------- classifier + log_softmax, GraphNorm-2 folded in-block ----------
__global__ __launch_bounds__(256) void classify(
    const unsigned short* __restrict__ h,
    const float* __restrict__ S, const float* __restrict__ gamma,
    const float* __restrict__ beta, const float* __restrict__ mscale,
    const float* __restrict__ W, const float* __restrict__ b,
    float* __restrict__ out, int n) {
  __shared__ float4 sW[64];
  __shared__ float sBt[256];
  __shared__ float sb[4];
  int tid = threadIdx.x;
  if (tid < 64) {
    float invn = 1.f / (float)n;
    float mu = S[tid] * invn;
    float ms = mscale[tid];
    float var = S[64 + tid] * invn - 2.f * ms * mu * mu + ms * ms * mu * mu;
    float A = gamma[tid] * rsqrtf(var + 1e-5f);
    float B = beta[tid] - A * ms * mu;
    float4 w = ((const float4*)W)[tid];
    sW[tid] = make_float4(A * w.x, A * w.y, A * w.z, A * w.w);
    sBt[tid * 4 + 0] = B * w.x; sBt[tid * 4 + 1] = B * w.y;
    sBt[tid * 4 + 2] = B * w.z; sBt[tid * 4 + 3] = B * w.w;
  }
  __syncthreads();
  if (tid < 4) {
    float s = b[tid];
    for (int c = 0; c < 64; c++) s += sBt[c * 4 + tid];
    sb[tid] = s;
  }
  __syncthreads();
  int node = blockIdx.x * 256 + tid;
  if (node >= n) return;
  float acc0 = sb[0], acc1 = sb[1], acc2 = sb[2], acc3 = sb[3];
  const uint4* row = (const uint4*)(h + (size_t)node * CCH);
#pragma unroll
  for (int k4 = 0; k4 < 8; k4++) {
    uint4 u = row[k4];
    float v[8];
    unpack8(u, v);
#pragma unroll
    for (int j = 0; j < 8; j++) {
      float4 w = sW[k4 * 8 + j];
      acc0 = fmaf(v[j], w.x, acc0);
      acc1 = fmaf(v[j], w.y, acc1);
      acc2 = fmaf(v[j], w.z, acc2);
      acc3 = fmaf(v[j], w.w, acc3);
    }
  }
  float mx = fmaxf(fmaxf(acc0, acc1), fmaxf(acc2, acc3));
  float s = __expf(acc0 - mx) + __expf(acc1 - mx) + __expf(acc2 - mx) + __expf(acc3 - mx);
  float lse = mx + logf(s);
  float4 o = make_float4(acc0 - lse, acc1 - lse, acc2 - lse, acc3 - lse);
  *((float4*)(out + (size_t)node * 4)) = o;
}

extern "C" void kernel_launch(void* const* d_in, const int* in_sizes, int n_in,
                              void* d_out, int out_size, void* d_ws, size_t ws_size,
                              hipStream_t stream) {
  const float* x     = (const float*)d_in[0];
  const int*   ei    = (const int*)d_in[1];
  const float* Wl1   = (const float*)d_in[2];
  const float* bl1   = (const float*)d_in[3];
  const float* Wr1   = (const float*)d_in[4];
  const float* br1   = (const float*)d_in[5];
  const float* att1  = (const float*)d_in[6];
  const float* bias1 = (const float*)d_in[7];
  const float* gng1  = (const float*)d_in[8];
  const float* gnb1  = (const float*)d_in[9];
  const float* gna1  = (const float*)d_in[10];
  const float* Wl2   = (const float*)d_in[11];
  const float* bl2   = (const float*)d_in[12];
  const float* Wr2   = (const float*)d_in[13];
  const float* br2   = (const float*)d_in[14];
  const float* att2  = (const float*)d_in[15];
  const float* bias2 = (const float*)d_in[16];
  const float* gng2  = (const float*)d_in[17];
  const float* gnb2  = (const float*)d_in[18];
  const float* gna2  = (const float*)d_in[19];
  const float* W1    = (const float*)d_in[20];
  const float* b1    = (const float*)d_in[21];

  const int N = in_sizes[0] / 128;
  const int E = in_sizes[1] / 2;
  const int EP = E + N;
  const int nB = (N + 127) >> 7;            // dst-buckets of 128 nodes
  const int chunk = (E + NBKE - 1) / NBKE;  // edges per binning block
  const int cap = ((E / nB) * 2 + 255) & ~255;  // strided ebuf capacity (+~22 sigma)

  // workspace layout: zeroed header [gCnt | S1 | S2 | done] first
  int* gCnt = (int*)d_ws;                        // 512 (bucket totals)
  float* S1  = (float*)(gCnt + 512);             // 128
  float* S2  = S1 + 128;                         // 128
  int* done  = (int*)(S2 + 128);                 // 64 (2 used)
  float* bl2p = (float*)(done + 64);             // 128
  float* br2p = bl2p + 128;                      // 128
  float* part1 = br2p + 128;                     // GSTB*128
  float* part2 = part1 + GSTB * 128;             // GSTB*128
  unsigned short* xb    = (unsigned short*)(part2 + GSTB * 128);  // N*128
  unsigned short* xlb   = xb + (size_t)N * HC;            // N*128
  unsigned short* xrb   = xlb + (size_t)N * HC;           // N*128
  unsigned short* aggb  = xrb + (size_t)N * HC;           // N*64
  unsigned short* Wl1tb = aggb + (size_t)N * CCH;         // 128*128
  unsigned short* Wr1tb = Wl1tb + HC * HC;                // 128*128
  unsigned short* Wl2tb = Wr1tb + HC * HC;                // 128*64
  unsigned short* Wr2tb = Wl2tb + HC * CCH;               // 128*64
  int* row_st  = (int*)(Wr2tb + HC * CCH);                // N
  int* deg     = row_st + N;                              // N
  unsigned* ebuf = (unsigned*)(deg + N);                  // nB*cap (strided)
  int* csr_src = (int*)(ebuf + (size_t)nB * cap);         // EP + 64 pad

  dim3 b256(256);
  const int gNode = (N * 64 + 255) / 256;
  const int gCls  = (N + 255) / 256;
  const int gCast = (N * 32 + 255) / 256;
  const int gGemm = (N + 31) / 32;

  // ---- zero header (gCnt + S1 + S2 + done) ----
  hipMemsetAsync(d_ws, 0, 4096, stream);

  // ---- K1: fused multisplit count+place ∥ casts ----
  binplace_cast<<<NBKE + gCast, b256, 0, stream>>>(
      ei, E, chunk, nB, cap, gCnt, ebuf,
      x, xb, N * 32, Wl1, Wr1, Wl1tb, Wr1tb);

  // ---- K2: per-bucket CSR build ∥ layer-1 GEMM ----
  csr_gemm1<<<nB + gGemm, b256, 0, stream>>>(
      ebuf, gCnt, cap, row_st, deg, csr_src, N, EP, nB,
      xb, Wl1tb, Wr1tb, bl1, br1, xlb, xrb, N);

  // ---- Layer 1 attention + fused stats/weight-fold (parallel tail) ----
  node_attn<<<gNode, b256, 0, stream>>>(xlb, xrb, csr_src, row_st, deg, att1, bias1, aggb, N);
  gn_stats_prep<<<GSTB, b256, 0, stream>>>(aggb, part1, S1, done, gng1, gnb1, gna1,
                                           Wl2, bl2, Wr2, br2,
                                           Wl2tb, bl2p, Wr2tb, br2p, N);

  // ---- Layer 2 ----
  gemm_mfma<64><<<gGemm, b256, 0, stream>>>(aggb, Wl2tb, Wr2tb, bl2p, br2p, xlb, xrb, N);
  node_attn<<<gNode, b256, 0, stream>>>(xlb, xrb, csr_src, row_st, deg, att2, bias2, aggb, N);
  gn_stats<<<GSTB, b256, 0, stream>>>(aggb, part2, S2, done + 1, N);

  // ---- Classifier (GraphNorm-2 folded in-block) ----
  classify<<<gCls, b256, 0, stream>>>(aggb, S2, gng2, gnb2, gna2, W1, b1,
                                      (float*)d_out, N);
}